// Round 10
// baseline (22.262 us; speedup 1.0000x reference)
//
#include <hip/hip_runtime.h>

#define NB 16
#define NA 3
#define NC 80
#define NH 76
#define NW 76
#define MAX_GT 50
#define PLANE (NH * NW)       // 5776
#define CH (5 + NC)           // 85
#define IMG 608.0f
#define OBJSC 5.0f
#define BLOCK 384                            // 6 waves
#define CPB 1444                             // 19 rows x 76; PLANE = 4*CPB exactly
#define BPP 4
#define GRID (NB * NA * BPP)                 // 192  (<= 256 CUs: ONE round)
#define NGRP 361                             // float4 groups per block (4 cells each)
#define KSIL 0.375f                          // SIL/(1+SIL), SIL=0.6

__device__ __constant__ float c_aw[3] = {1.5f, 2.375f, 5.0f};
__device__ __constant__ float c_ah[3] = {2.0f, 4.5f, 3.5f};

__device__ inline float fast_sigmoid(float v) {
    return __builtin_amdgcn_rcpf(1.f + __expf(-v));
}

__device__ inline float iou_full(float x1, float y1, float w1, float h1,
                                 float x2, float y2, float w2, float h2) {
    float mx = fminf(x1 - w1 * 0.5f, x2 - w2 * 0.5f);
    float Mx = fmaxf(x1 + w1 * 0.5f, x2 + w2 * 0.5f);
    float my = fminf(y1 - h1 * 0.5f, y2 - h2 * 0.5f);
    float My = fmaxf(y1 + h1 * 0.5f, y2 + h2 * 0.5f);
    float cw = w1 + w2 - (Mx - mx);
    float ch = h1 + h2 - (My - my);
    float carea = (cw <= 0.f || ch <= 0.f) ? 0.f : cw * ch;
    float uarea = w1 * h1 + w2 * h2 - carea;
    return carea / uarea;
}

// One-round fused kernel: 192 blocks (<=256 CUs), 384 threads, 4 cells/thread
// via one aligned float4 group. Wave-0 single-round prep (target only);
// last-write-wins scatter via LDS atomicMax; CE (incl. deferred GT-cell conf
// term) prefetched per wave and hidden under the dense phase.
__global__ __launch_bounds__(BLOCK) void yolo_fused(const float* __restrict__ out,
                                                    const float* __restrict__ target,
                                                    float* __restrict__ partial) {
    const int bid = blockIdx.x;
    const int plane_id = bid / BPP;
    const int cb = bid % BPP;
    const int b = plane_id / NA;
    const int a = plane_id % NA;
    const int t = threadIdx.x;
    const int cell0 = cb * CPB + 4 * t;      // 16B-aligned group base
    const bool valid = (t < NGRP);
    const float jminf = (float)(cb * 19);
    const float jmaxf = (float)(cb * 19 + 18);

    __shared__ float4 s_gtA[MAX_GT];          // culled: xlo, xhi, ylo, yhi
    __shared__ float4 s_gtB[MAX_GT];          // culled: gw, gh, KSIL*area, 0
    __shared__ float s_ent[MAX_GT][12];       // 1:tx 2:ty 3:tw 4:th 5:gx 6:cls 7:gy 8:gw 9:gh 10:aw 11:ah
    __shared__ int s_ovr[CPB];                // local cell -> GT index (atomicMax)
    __shared__ int s_ce_cell[MAX_GT];
    __shared__ int s_ce_ov[MAX_GT];
    __shared__ int s_nv, s_nk, s_nce;
    __shared__ float s_red[BLOCK / 64];

    // ---- dense channel loads: one float4 per channel, issued first ----
    const float* base = out + ((size_t)(b * NA + a) * CH) * PLANE;
    float4 c0 = {0,0,0,0}, c1 = {0,0,0,0}, c2 = {0,0,0,0}, c3 = {0,0,0,0}, c4 = {0,0,0,0};
    if (valid) {
        c0 = *(const float4*)&base[cell0];
        c1 = *(const float4*)&base[cell0 + PLANE];
        c2 = *(const float4*)&base[cell0 + 2 * (size_t)PLANE];
        c3 = *(const float4*)&base[cell0 + 3 * (size_t)PLANE];
        c4 = *(const float4*)&base[cell0 + 4 * (size_t)PLANE];
    }

    for (int i = t; i < CPB; i += BLOCK) s_ovr[i] = -1;
    if (t == 0) s_nce = 0;

    // ---- prep: wave 0 only, ONE memory round (target only) ----
    int key = -1;
    if (t < 64) {
        float pxr = 1.f;
        float xlo = 0.f, xhi = 0.f, ylo = 0.f, yhi = 0.f, gw = 0.f, gh = 0.f;
        if (t < MAX_GT) {
            const float* tg = target + (size_t)b * MAX_GT * 5 + t * 5;
            float gcls = tg[0];
            pxr = tg[1];
            float gx = tg[1] * (float)NW / IMG;
            float gy = tg[2] * (float)NH / IMG;
            gw = tg[3] * (float)NW / IMG;
            gh = tg[4] * (float)NH / IMG;
            xlo = gx - 0.5f * gw; xhi = gx + 0.5f * gw;
            ylo = gy - 0.5f * gh; yhi = gy + 0.5f * gh;

            int bn = 0; float best = -1.f;
            #pragma unroll
            for (int aa = 0; aa < NA; aa++) {
                float ca = fminf(gw, c_aw[aa]) * fminf(gh, c_ah[aa]);
                float ua = gw * gh + c_aw[aa] * c_ah[aa] - ca;
                float v = ca / ua;
                if (v > best) { best = v; bn = aa; }
            }
            int gi = (int)gx, gj = (int)gy;

            key = (gi >= 0 && gi < NW && gj >= 0 && gj < NH)
                      ? ((bn * NH + gj) * NW + gi) : -1;
            s_ent[t][1] = gx - (float)gi;
            s_ent[t][2] = gy - (float)gj;
            s_ent[t][3] = __logf(gw / c_aw[bn]);
            s_ent[t][4] = __logf(gh / c_ah[bn]);
            s_ent[t][5] = gx;
            s_ent[t][6] = gcls;
            s_ent[t][7] = gy;
            s_ent[t][8] = gw;
            s_ent[t][9] = gh;
            s_ent[t][10] = c_aw[bn];
            s_ent[t][11] = c_ah[bn];
        }
        unsigned long long zm = __ballot((t < MAX_GT) && (pxr == 0.f));
        int nv = zm ? (int)(__ffsll((long long)zm) - 1) : MAX_GT;
        if (t == 0) s_nv = nv;

        // Y-band cull (conservative; R7 derivation)
        bool keep = (t < nv) &&
                    (jmaxf + 0.75f > ylo - 0.25f * gh - 1.0f) &&
                    (jminf - 0.75f < yhi + 0.25f * gh);
        unsigned long long km = __ballot(keep);
        if (keep) {
            int pos = (int)__popcll(km & ((1ull << t) - 1ull));
            s_gtA[pos] = make_float4(xlo, xhi, ylo, yhi);
            s_gtB[pos] = make_float4(gw, gh, KSIL * gw * gh, 0.f);
        }
        if (t == 0) s_nk = (int)__popcll(km);
    }
    __syncthreads();

    // ---- scatter: last-write-wins = highest GT index via atomicMax ----
    if (t < s_nv && key >= 0) {
        int ae = key / PLANE;
        int local = (key - ae * PLANE) - cb * CPB;
        if (ae == a && local >= 0 && local < CPB) atomicMax(&s_ovr[local], t);
    }
    __syncthreads();

    // ---- per-cell overrides + CE list ----
    int ov[4] = {-1, -1, -1, -1};
    if (valid) {
        #pragma unroll
        for (int k = 0; k < 4; k++) {
            ov[k] = s_ovr[4 * t + k];
            if (ov[k] >= 0) {
                int idx = atomicAdd(&s_nce, 1);
                s_ce_cell[idx] = cell0 + k;
                s_ce_ov[idx] = ov[k];
            }
        }
    }
    __syncthreads();

    const int nce = s_nce;
    const int wid = t >> 6, lane = t & 63;
    const float* cls_base = base + 5 * (size_t)PLANE;

    // ---- CE prefetch: one entry per wave (6 waves), issued BEFORE dense ----
    float ce1 = 0.f, ce2 = -3.4e38f, celt = 0.f;
    float q0 = 0.f, q1 = 0.f, q2 = 0.f, q3 = 0.f, q4 = 0.f;
    int pcell = 0, pov = 0;
    const bool havece = (wid < nce);
    if (havece) {
        pcell = s_ce_cell[wid];
        pov = s_ce_ov[wid];
        int ccls = (int)s_ent[pov][6];
        const float* cb0 = cls_base + pcell;
        ce1 = cb0[(size_t)lane * PLANE];
        if (lane < NC - 64) ce2 = cb0[(size_t)(lane + 64) * PLANE];
        celt = cb0[(size_t)ccls * PLANE];
        if (lane == 0) {
            q0 = base[pcell];
            q1 = base[pcell + PLANE];
            q2 = base[pcell + 2 * (size_t)PLANE];
            q3 = base[pcell + 3 * (size_t)PLANE];
            q4 = base[pcell + 4 * (size_t)PLANE];
        }
    }

    // ---- dense loss: 4 cells/thread, GT reads shared across all 4 ----
    float loss = 0.f;
    if (valid) {
        const float o2a[4] = {c2.x, c2.y, c2.z, c2.w};
        const float o3a[4] = {c3.x, c3.y, c3.z, c3.w};
        float xs[4], ys[4], cfs[4], pws[4], phs[4];
        float xl[4], xh[4], yl[4], yh[4], kpa[4];
        bool sil[4];
        {
            const float o0a[4] = {c0.x, c0.y, c0.z, c0.w};
            const float o1a[4] = {c1.x, c1.y, c1.z, c1.w};
            const float o4a[4] = {c4.x, c4.y, c4.z, c4.w};
            int j0 = cell0 / NW, i0 = cell0 - j0 * NW;   // row fixed within group? i0+3<=75?
            #pragma unroll
            for (int k = 0; k < 4; k++) {
                int cc = cell0 + k;
                int j = cc / NW, i = cc - j * NW;        // groups may straddle rows
                xs[k] = fast_sigmoid(o0a[k]);
                ys[k] = fast_sigmoid(o1a[k]);
                cfs[k] = fast_sigmoid(o4a[k]);
                pws[k] = __expf(o2a[k]) * c_aw[a];
                phs[k] = __expf(o3a[k]) * c_ah[a];
                float px = xs[k] + (float)i, py = ys[k] + (float)j;
                xl[k] = px - 0.5f * pws[k]; xh[k] = px + 0.5f * pws[k];
                yl[k] = py - 0.5f * phs[k]; yh[k] = py + 0.5f * phs[k];
                kpa[k] = KSIL * pws[k] * phs[k];
                sil[k] = false;
            }
            (void)j0; (void)i0;
        }

        int nk = s_nk;
        for (int tt = 0; tt < nk; tt++) {
            float4 gA = s_gtA[tt];
            float4 gB = s_gtB[tt];
            #pragma unroll
            for (int k = 0; k < 4; k++) {
                float mx = fminf(xl[k], gA.x), Mx = fmaxf(xh[k], gA.y);
                float my = fminf(yl[k], gA.z), My = fmaxf(yh[k], gA.w);
                float cw = (pws[k] + gB.x) - (Mx - mx);
                float ch = (phs[k] + gB.y) - (My - my);
                sil[k] |= (fminf(cw, ch) > 0.f) & (cw * ch > kpa[k] + gB.z);
            }
        }

        #pragma unroll
        for (int k = 0; k < 4; k++) {
            // conf term: non-GT cells only (GT-cell conf handled in CE phase)
            float cm = (ov[k] >= 0) ? 0.f : (sil[k] ? 0.f : 1.f);
            float tx = 0.5f, ty = 0.5f, tw = 0.f, th = 0.f;
            if (ov[k] >= 0) {
                tx = s_ent[ov[k]][1]; ty = s_ent[ov[k]][2];
                tw = s_ent[ov[k]][3]; th = s_ent[ov[k]][4];
            }
            float dx = xs[k] - tx, dy = ys[k] - ty;
            float dw = o2a[k] - tw, dh = o3a[k] - th;
            loss += 0.5f * (dx * dx + dy * dy + dw * dw + dh * dh
                            + cm * cfs[k] * cfs[k]);
        }
    }

    // ---- CE finish (prefetched entry): softmax-CE + deferred GT conf ----
    if (havece) {
        float m = fmaxf(ce1, ce2);
        #pragma unroll
        for (int off = 32; off; off >>= 1) m = fmaxf(m, __shfl_xor(m, off));
        float e = __expf(ce1 - m) + ((lane < NC - 64) ? __expf(ce2 - m) : 0.f);
        #pragma unroll
        for (int off = 32; off; off >>= 1) e += __shfl_xor(e, off);
        if (lane == 0) {
            int gjc = pcell / NW, gic = pcell - gjc * NW;
            float ppx = fast_sigmoid(q0) + (float)gic;
            float ppy = fast_sigmoid(q1) + (float)gjc;
            float ppw = __expf(q2) * s_ent[pov][10];
            float pph = __expf(q3) * s_ent[pov][11];
            float iou = iou_full(s_ent[pov][5], s_ent[pov][7],
                                 s_ent[pov][8], s_ent[pov][9],
                                 ppx, ppy, ppw, pph);
            float dcf = fast_sigmoid(q4) - iou;
            loss += m + __logf(e) - celt + 0.5f * OBJSC * dcf * dcf;
        }
    }
    // leftover CE entries (blocks with >6 GT cells)
    for (int k = wid + BLOCK / 64; k < nce; k += BLOCK / 64) {
        int ccell = s_ce_cell[k];
        int ovk = s_ce_ov[k];
        int ccls = (int)s_ent[ovk][6];
        const float* cb0 = cls_base + ccell;
        float w1 = cb0[(size_t)lane * PLANE];
        float w2 = (lane < NC - 64) ? cb0[(size_t)(lane + 64) * PLANE] : -3.4e38f;
        float m = fmaxf(w1, w2);
        #pragma unroll
        for (int off = 32; off; off >>= 1) m = fmaxf(m, __shfl_xor(m, off));
        float e = __expf(w1 - m) + ((lane < NC - 64) ? __expf(w2 - m) : 0.f);
        #pragma unroll
        for (int off = 32; off; off >>= 1) e += __shfl_xor(e, off);
        if (lane == 0) {
            int gjc = ccell / NW, gic = ccell - gjc * NW;
            float r0 = base[ccell];
            float r1 = base[ccell + PLANE];
            float r2 = base[ccell + 2 * (size_t)PLANE];
            float r3 = base[ccell + 3 * (size_t)PLANE];
            float r4 = base[ccell + 4 * (size_t)PLANE];
            float ppx = fast_sigmoid(r0) + (float)gic;
            float ppy = fast_sigmoid(r1) + (float)gjc;
            float ppw = __expf(r2) * s_ent[ovk][10];
            float pph = __expf(r3) * s_ent[ovk][11];
            float iou = iou_full(s_ent[ovk][5], s_ent[ovk][7],
                                 s_ent[ovk][8], s_ent[ovk][9],
                                 ppx, ppy, ppw, pph);
            float dcf = fast_sigmoid(r4) - iou;
            loss += m + __logf(e) - cb0[(size_t)ccls * PLANE]
                    + 0.5f * OBJSC * dcf * dcf;
        }
    }

    // ---- block reduction -> partial store ----
    #pragma unroll
    for (int off = 32; off; off >>= 1) loss += __shfl_down(loss, off);
    if (lane == 0) s_red[wid] = loss;
    __syncthreads();
    if (t == 0) {
        float s = 0.f;
        #pragma unroll
        for (int q = 0; q < BLOCK / 64; q++) s += s_red[q];
        partial[bid] = s;
    }
}

// Final reduction: one block sums the 192 per-block partials.
__global__ __launch_bounds__(256) void yolo_reduce(const float* __restrict__ partial,
                                                   float* __restrict__ d_out) {
    int t = threadIdx.x;
    __shared__ float s_red[4];
    float s = 0.f;
    for (int i = t; i < GRID; i += 256) s += partial[i];
    #pragma unroll
    for (int off = 32; off; off >>= 1) s += __shfl_down(s, off);
    if ((t & 63) == 0) s_red[t >> 6] = s;
    __syncthreads();
    if (t == 0) {
        float tot = 0.f;
        #pragma unroll
        for (int q = 0; q < 4; q++) tot += s_red[q];
        d_out[0] = tot;
    }
}

extern "C" void kernel_launch(void* const* d_in, const int* in_sizes, int n_in,
                              void* d_out, int out_size, void* d_ws, size_t ws_size,
                              hipStream_t stream) {
    const float* out = (const float*)d_in[0];
    const float* target = (const float*)d_in[1];
    float* partial = (float*)d_ws;
    float* o = (float*)d_out;

    hipLaunchKernelGGL(yolo_fused, dim3(GRID), dim3(BLOCK), 0, stream,
                       out, target, partial);
    hipLaunchKernelGGL(yolo_reduce, dim3(1), dim3(256), 0, stream,
                       partial, o);
}

// Round 11
// 15.701 us; speedup vs baseline: 1.4179x; 1.4179x over previous
//
#include <hip/hip_runtime.h>

#define NB 16
#define NA 3
#define NC 80
#define NH 76
#define NW 76
#define MAX_GT 50
#define PLANE (NH * NW)       // 5776
#define CH (5 + NC)           // 85
#define IMG 608.0f
#define OBJSC 5.0f
#define BLOCK 512                            // 8 waves, 1 cell/thread
#define CPB 512
#define BPP ((PLANE + CPB - 1) / CPB)        // 12
#define GRID (NB * NA * BPP)                 // 576
#define KSIL 0.375f                          // SIL/(1+SIL), SIL=0.6

__device__ __constant__ float c_aw[3] = {1.5f, 2.375f, 5.0f};
__device__ __constant__ float c_ah[3] = {2.0f, 4.5f, 3.5f};

__device__ inline float fast_sigmoid(float v) {
    return __builtin_amdgcn_rcpf(1.f + __expf(-v));
}

__device__ inline float iou_full(float x1, float y1, float w1, float h1,
                                 float x2, float y2, float w2, float h2) {
    float mx = fminf(x1 - w1 * 0.5f, x2 - w2 * 0.5f);
    float Mx = fmaxf(x1 + w1 * 0.5f, x2 + w2 * 0.5f);
    float my = fminf(y1 - h1 * 0.5f, y2 - h2 * 0.5f);
    float My = fmaxf(y1 + h1 * 0.5f, y2 + h2 * 0.5f);
    float cw = w1 + w2 - (Mx - mx);
    float ch = h1 + h2 - (My - my);
    float carea = (cw <= 0.f || ch <= 0.f) ? 0.f : cw * ch;
    float uarea = w1 * h1 + w2 * h2 - carea;
    return carea / uarea;
}

// R8 skeleton, BLOCK=512 / 1 cell-per-thread: 18 waves/CU (4.5/SIMD) for
// latency hiding. Wave-0 single-round prep; atomicMax last-write-wins scatter;
// CE (incl. deferred GT-cell conf) prefetched per wave, hidden under dense.
__global__ __launch_bounds__(BLOCK) void yolo_fused(const float* __restrict__ out,
                                                    const float* __restrict__ target,
                                                    float* __restrict__ partial) {
    const int bid = blockIdx.x;
    const int plane_id = bid / BPP;
    const int cb = bid % BPP;
    const int b = plane_id / NA;
    const int a = plane_id % NA;
    const int t = threadIdx.x;
    const int cell = cb * CPB + t;
    const bool valid = (cell < PLANE);
    const float jminf = (float)((cb * CPB) / NW);
    const float jmaxf = (float)((min(cb * CPB + CPB, PLANE) - 1) / NW);

    __shared__ float4 s_gtA[MAX_GT];          // culled: xlo, xhi, ylo, yhi
    __shared__ float4 s_gtB[MAX_GT];          // culled: gw, gh, KSIL*area, 0
    __shared__ float s_ent[MAX_GT][12];       // 1:tx 2:ty 3:tw 4:th 5:gx 6:cls 7:gy 8:gw 9:gh 10:aw 11:ah
    __shared__ int s_ovr[CPB];                // local cell -> GT index (atomicMax)
    __shared__ int s_ce_cell[MAX_GT];
    __shared__ int s_ce_ov[MAX_GT];
    __shared__ int s_nv, s_nk, s_nce;
    __shared__ float s_red[BLOCK / 64];

    // ---- dense channel loads (scalar, coalesced), issued first ----
    const float* base = out + ((size_t)(b * NA + a) * CH) * PLANE;
    float o0 = 0.f, o1 = 0.f, o2 = 0.f, o3 = 0.f, o4 = 0.f;
    if (valid) {
        o0 = base[cell];
        o1 = base[cell + PLANE];
        o2 = base[cell + 2 * (size_t)PLANE];
        o3 = base[cell + 3 * (size_t)PLANE];
        o4 = base[cell + 4 * (size_t)PLANE];
    }

    s_ovr[t] = -1;
    if (t == 0) s_nce = 0;

    // ---- prep: wave 0 only, ONE memory round (target only) ----
    int key = -1;
    if (t < 64) {
        float pxr = 1.f;
        float xlo = 0.f, xhi = 0.f, ylo = 0.f, yhi = 0.f, gw = 0.f, gh = 0.f;
        if (t < MAX_GT) {
            const float* tg = target + (size_t)b * MAX_GT * 5 + t * 5;
            float gcls = tg[0];
            pxr = tg[1];
            float gx = tg[1] * (float)NW / IMG;
            float gy = tg[2] * (float)NH / IMG;
            gw = tg[3] * (float)NW / IMG;
            gh = tg[4] * (float)NH / IMG;
            xlo = gx - 0.5f * gw; xhi = gx + 0.5f * gw;
            ylo = gy - 0.5f * gh; yhi = gy + 0.5f * gh;

            int bn = 0; float best = -1.f;
            #pragma unroll
            for (int aa = 0; aa < NA; aa++) {
                float ca = fminf(gw, c_aw[aa]) * fminf(gh, c_ah[aa]);
                float ua = gw * gh + c_aw[aa] * c_ah[aa] - ca;
                float v = ca / ua;
                if (v > best) { best = v; bn = aa; }
            }
            int gi = (int)gx, gj = (int)gy;

            key = (gi >= 0 && gi < NW && gj >= 0 && gj < NH)
                      ? ((bn * NH + gj) * NW + gi) : -1;
            s_ent[t][1] = gx - (float)gi;
            s_ent[t][2] = gy - (float)gj;
            s_ent[t][3] = __logf(gw / c_aw[bn]);
            s_ent[t][4] = __logf(gh / c_ah[bn]);
            s_ent[t][5] = gx;
            s_ent[t][6] = gcls;
            s_ent[t][7] = gy;
            s_ent[t][8] = gw;
            s_ent[t][9] = gh;
            s_ent[t][10] = c_aw[bn];
            s_ent[t][11] = c_ah[bn];
        }
        unsigned long long zm = __ballot((t < MAX_GT) && (pxr == 0.f));
        int nv = zm ? (int)(__ffsll((long long)zm) - 1) : MAX_GT;
        if (t == 0) s_nv = nv;

        // Y-band cull (conservative; R7 derivation)
        bool keep = (t < nv) &&
                    (jmaxf + 0.75f > ylo - 0.25f * gh - 1.0f) &&
                    (jminf - 0.75f < yhi + 0.25f * gh);
        unsigned long long km = __ballot(keep);
        if (keep) {
            int pos = (int)__popcll(km & ((1ull << t) - 1ull));
            s_gtA[pos] = make_float4(xlo, xhi, ylo, yhi);
            s_gtB[pos] = make_float4(gw, gh, KSIL * gw * gh, 0.f);
        }
        if (t == 0) s_nk = (int)__popcll(km);
    }
    __syncthreads();

    // ---- scatter: last-write-wins = highest GT index via atomicMax ----
    if (t < s_nv && key >= 0) {
        int ae = key / PLANE;
        int local = (key - ae * PLANE) - cb * CPB;
        if (ae == a && local >= 0 && local < CPB) atomicMax(&s_ovr[local], t);
    }
    __syncthreads();

    // ---- per-cell override + CE list ----
    int ov = valid ? s_ovr[t] : -1;
    if (ov >= 0) {
        int idx = atomicAdd(&s_nce, 1);
        s_ce_cell[idx] = cell;
        s_ce_ov[idx] = ov;
    }
    __syncthreads();

    const int nce = s_nce;
    const int wid = t >> 6, lane = t & 63;
    const float* cls_base = base + 5 * (size_t)PLANE;

    // ---- CE prefetch: one entry per wave (8 waves), issued BEFORE dense ----
    float ce1 = 0.f, ce2 = -3.4e38f, celt = 0.f;
    float q0 = 0.f, q1 = 0.f, q2 = 0.f, q3 = 0.f, q4 = 0.f;
    int pcell = 0, pov = 0;
    const bool havece = (wid < nce);
    if (havece) {
        pcell = s_ce_cell[wid];
        pov = s_ce_ov[wid];
        int ccls = (int)s_ent[pov][6];
        const float* cb0 = cls_base + pcell;
        ce1 = cb0[(size_t)lane * PLANE];
        if (lane < NC - 64) ce2 = cb0[(size_t)(lane + 64) * PLANE];
        celt = cb0[(size_t)ccls * PLANE];
        if (lane == 0) {
            q0 = base[pcell];
            q1 = base[pcell + PLANE];
            q2 = base[pcell + 2 * (size_t)PLANE];
            q3 = base[pcell + 3 * (size_t)PLANE];
            q4 = base[pcell + 4 * (size_t)PLANE];
        }
    }

    // ---- dense loss (1 cell) ----
    float loss = 0.f;
    if (valid) {
        int j = cell / NW, i = cell - (cell / NW) * NW;
        float x = fast_sigmoid(o0), y = fast_sigmoid(o1), cf = fast_sigmoid(o4);
        float pw = __expf(o2) * c_aw[a], ph = __expf(o3) * c_ah[a];
        float px = x + (float)i, py = y + (float)j;
        float xl = px - 0.5f * pw, xh = px + 0.5f * pw;
        float yl = py - 0.5f * ph, yh = py + 0.5f * ph;
        float kpa = KSIL * pw * ph;

        bool sil = false;
        int nk = s_nk;
        #pragma unroll 2
        for (int tt = 0; tt < nk; tt++) {
            float4 gA = s_gtA[tt];
            float4 gB = s_gtB[tt];
            float mx = fminf(xl, gA.x), Mx = fmaxf(xh, gA.y);
            float my = fminf(yl, gA.z), My = fmaxf(yh, gA.w);
            float cw = (pw + gB.x) - (Mx - mx);
            float ch = (ph + gB.y) - (My - my);
            sil |= (fminf(cw, ch) > 0.f) & (cw * ch > kpa + gB.z);
        }

        // conf term: non-GT cells only (GT-cell conf handled in CE phase)
        float cm = (ov >= 0) ? 0.f : (sil ? 0.f : 1.f);
        float tx = 0.5f, ty = 0.5f, tw = 0.f, th = 0.f;
        if (ov >= 0) {
            tx = s_ent[ov][1]; ty = s_ent[ov][2];
            tw = s_ent[ov][3]; th = s_ent[ov][4];
        }
        float dx = x - tx, dy = y - ty, dw = o2 - tw, dh = o3 - th;
        loss = 0.5f * (dx * dx + dy * dy + dw * dw + dh * dh + cm * cf * cf);
    }

    // ---- CE finish (prefetched entry): softmax-CE + deferred GT conf ----
    if (havece) {
        float m = fmaxf(ce1, ce2);
        #pragma unroll
        for (int off = 32; off; off >>= 1) m = fmaxf(m, __shfl_xor(m, off));
        float e = __expf(ce1 - m) + ((lane < NC - 64) ? __expf(ce2 - m) : 0.f);
        #pragma unroll
        for (int off = 32; off; off >>= 1) e += __shfl_xor(e, off);
        if (lane == 0) {
            int gjc = pcell / NW, gic = pcell - gjc * NW;
            float ppx = fast_sigmoid(q0) + (float)gic;
            float ppy = fast_sigmoid(q1) + (float)gjc;
            float ppw = __expf(q2) * s_ent[pov][10];
            float pph = __expf(q3) * s_ent[pov][11];
            float iou = iou_full(s_ent[pov][5], s_ent[pov][7],
                                 s_ent[pov][8], s_ent[pov][9],
                                 ppx, ppy, ppw, pph);
            float dcf = fast_sigmoid(q4) - iou;
            loss += m + __logf(e) - celt + 0.5f * OBJSC * dcf * dcf;
        }
    }
    // leftover CE entries (rare: >8 GT cells in one chunk)
    for (int k = wid + BLOCK / 64; k < nce; k += BLOCK / 64) {
        int ccell = s_ce_cell[k];
        int ovk = s_ce_ov[k];
        int ccls = (int)s_ent[ovk][6];
        const float* cb0 = cls_base + ccell;
        float w1 = cb0[(size_t)lane * PLANE];
        float w2 = (lane < NC - 64) ? cb0[(size_t)(lane + 64) * PLANE] : -3.4e38f;
        float m = fmaxf(w1, w2);
        #pragma unroll
        for (int off = 32; off; off >>= 1) m = fmaxf(m, __shfl_xor(m, off));
        float e = __expf(w1 - m) + ((lane < NC - 64) ? __expf(w2 - m) : 0.f);
        #pragma unroll
        for (int off = 32; off; off >>= 1) e += __shfl_xor(e, off);
        if (lane == 0) {
            int gjc = ccell / NW, gic = ccell - gjc * NW;
            float r0 = base[ccell];
            float r1 = base[ccell + PLANE];
            float r2 = base[ccell + 2 * (size_t)PLANE];
            float r3 = base[ccell + 3 * (size_t)PLANE];
            float r4 = base[ccell + 4 * (size_t)PLANE];
            float ppx = fast_sigmoid(r0) + (float)gic;
            float ppy = fast_sigmoid(r1) + (float)gjc;
            float ppw = __expf(r2) * s_ent[ovk][10];
            float pph = __expf(r3) * s_ent[ovk][11];
            float iou = iou_full(s_ent[ovk][5], s_ent[ovk][7],
                                 s_ent[ovk][8], s_ent[ovk][9],
                                 ppx, ppy, ppw, pph);
            float dcf = fast_sigmoid(r4) - iou;
            loss += m + __logf(e) - cb0[(size_t)ccls * PLANE]
                    + 0.5f * OBJSC * dcf * dcf;
        }
    }

    // ---- block reduction -> partial store ----
    #pragma unroll
    for (int off = 32; off; off >>= 1) loss += __shfl_down(loss, off);
    if (lane == 0) s_red[wid] = loss;
    __syncthreads();
    if (t == 0) {
        float s = 0.f;
        #pragma unroll
        for (int q = 0; q < BLOCK / 64; q++) s += s_red[q];
        partial[bid] = s;
    }
}

// Final reduction: one block sums the 576 per-block partials.
__global__ __launch_bounds__(256) void yolo_reduce(const float* __restrict__ partial,
                                                   float* __restrict__ d_out) {
    int t = threadIdx.x;
    __shared__ float s_red[4];
    float s = 0.f;
    for (int i = t; i < GRID; i += 256) s += partial[i];
    #pragma unroll
    for (int off = 32; off; off >>= 1) s += __shfl_down(s, off);
    if ((t & 63) == 0) s_red[t >> 6] = s;
    __syncthreads();
    if (t == 0) {
        float tot = 0.f;
        #pragma unroll
        for (int q = 0; q < 4; q++) tot += s_red[q];
        d_out[0] = tot;
    }
}

extern "C" void kernel_launch(void* const* d_in, const int* in_sizes, int n_in,
                              void* d_out, int out_size, void* d_ws, size_t ws_size,
                              hipStream_t stream) {
    const float* out = (const float*)d_in[0];
    const float* target = (const float*)d_in[1];
    float* partial = (float*)d_ws;
    float* o = (float*)d_out;

    hipLaunchKernelGGL(yolo_fused, dim3(GRID), dim3(BLOCK), 0, stream,
                       out, target, partial);
    hipLaunchKernelGGL(yolo_reduce, dim3(1), dim3(256), 0, stream,
                       partial, o);
}

// Round 12
// 15.412 us; speedup vs baseline: 1.4445x; 1.0187x over previous
//
#include <hip/hip_runtime.h>

#define NB 16
#define NA 3
#define NC 80
#define NH 76
#define NW 76
#define MAX_GT 50
#define PLANE (NH * NW)       // 5776
#define CH (5 + NC)           // 85
#define IMG 608.0f
#define OBJSC 5.0f
#define BLOCK 512                            // 8 waves, 1 cell/thread
#define CPB 512
#define BPP ((PLANE + CPB - 1) / CPB)        // 12
#define GRID (NB * NA * BPP)                 // 576
#define KSIL 0.375f                          // SIL/(1+SIL), SIL=0.6

__device__ __constant__ float c_aw[3] = {1.5f, 2.375f, 5.0f};
__device__ __constant__ float c_ah[3] = {2.0f, 4.5f, 3.5f};

__device__ inline float fast_sigmoid(float v) {
    return __builtin_amdgcn_rcpf(1.f + __expf(-v));
}

__device__ inline float iou_full(float x1, float y1, float w1, float h1,
                                 float x2, float y2, float w2, float h2) {
    float mx = fminf(x1 - w1 * 0.5f, x2 - w2 * 0.5f);
    float Mx = fmaxf(x1 + w1 * 0.5f, x2 + w2 * 0.5f);
    float my = fminf(y1 - h1 * 0.5f, y2 - h2 * 0.5f);
    float My = fmaxf(y1 + h1 * 0.5f, y2 + h2 * 0.5f);
    float cw = w1 + w2 - (Mx - mx);
    float ch = h1 + h2 - (My - my);
    float carea = (cw <= 0.f || ch <= 0.f) ? 0.f : cw * ch;
    float uarea = w1 * h1 + w2 * h2 - carea;
    return carea / uarea;
}

// R11 skeleton with the prep/scatter/CE-list phases fully contained in wave 0
// (LDS ops within one wave are ordered -> no intermediate barriers needed).
// ONE __syncthreads before the dense phase. 8 waves, 1 cell/thread.
__global__ __launch_bounds__(BLOCK) void yolo_fused(const float* __restrict__ out,
                                                    const float* __restrict__ target,
                                                    float* __restrict__ partial) {
    const int bid = blockIdx.x;
    const int plane_id = bid / BPP;
    const int cb = bid % BPP;
    const int b = plane_id / NA;
    const int a = plane_id % NA;
    const int t = threadIdx.x;
    const int cell = cb * CPB + t;
    const bool valid = (cell < PLANE);
    const float jminf = (float)((cb * CPB) / NW);
    const float jmaxf = (float)((min(cb * CPB + CPB, PLANE) - 1) / NW);

    __shared__ float4 s_gtA[MAX_GT];          // culled: xlo, xhi, ylo, yhi
    __shared__ float4 s_gtB[MAX_GT];          // culled: gw, gh, KSIL*area, 0
    __shared__ float s_ent[MAX_GT][12];       // 1:tx 2:ty 3:tw 4:th 5:gx 6:cls 7:gy 8:gw 9:gh 10:aw 11:ah
    __shared__ int s_ovr[CPB];                // local cell -> GT index (atomicMax)
    __shared__ int s_ce_cell[MAX_GT];
    __shared__ int s_ce_ov[MAX_GT];
    __shared__ int s_nk, s_nce;
    __shared__ float s_red[BLOCK / 64];

    // ---- dense channel loads (scalar, coalesced), issued first ----
    const float* base = out + ((size_t)(b * NA + a) * CH) * PLANE;
    float o0 = 0.f, o1 = 0.f, o2 = 0.f, o3 = 0.f, o4 = 0.f;
    if (valid) {
        o0 = base[cell];
        o1 = base[cell + PLANE];
        o2 = base[cell + 2 * (size_t)PLANE];
        o3 = base[cell + 3 * (size_t)PLANE];
        o4 = base[cell + 4 * (size_t)PLANE];
    }

    // ---- wave 0: init + prep + scatter + winner/CE-list (no barriers) ----
    if (t < 64) {
        #pragma unroll
        for (int i = 0; i < CPB / 64; i++) s_ovr[t + 64 * i] = -1;
        if (t == 0) s_nce = 0;

        float pxr = 1.f;
        float xlo = 0.f, xhi = 0.f, ylo = 0.f, yhi = 0.f, gw = 0.f, gh = 0.f;
        int key = -1;
        if (t < MAX_GT) {
            const float* tg = target + (size_t)b * MAX_GT * 5 + t * 5;
            float gcls = tg[0];
            pxr = tg[1];
            float gx = tg[1] * (float)NW / IMG;
            float gy = tg[2] * (float)NH / IMG;
            gw = tg[3] * (float)NW / IMG;
            gh = tg[4] * (float)NH / IMG;
            xlo = gx - 0.5f * gw; xhi = gx + 0.5f * gw;
            ylo = gy - 0.5f * gh; yhi = gy + 0.5f * gh;

            int bn = 0; float best = -1.f;
            #pragma unroll
            for (int aa = 0; aa < NA; aa++) {
                float ca = fminf(gw, c_aw[aa]) * fminf(gh, c_ah[aa]);
                float ua = gw * gh + c_aw[aa] * c_ah[aa] - ca;
                float v = ca / ua;
                if (v > best) { best = v; bn = aa; }
            }
            int gi = (int)gx, gj = (int)gy;

            key = (gi >= 0 && gi < NW && gj >= 0 && gj < NH)
                      ? ((bn * NH + gj) * NW + gi) : -1;
            s_ent[t][1] = gx - (float)gi;
            s_ent[t][2] = gy - (float)gj;
            s_ent[t][3] = __logf(gw / c_aw[bn]);
            s_ent[t][4] = __logf(gh / c_ah[bn]);
            s_ent[t][5] = gx;
            s_ent[t][6] = gcls;
            s_ent[t][7] = gy;
            s_ent[t][8] = gw;
            s_ent[t][9] = gh;
            s_ent[t][10] = c_aw[bn];
            s_ent[t][11] = c_ah[bn];
        }
        unsigned long long zm = __ballot((t < MAX_GT) && (pxr == 0.f));
        int nv = zm ? (int)(__ffsll((long long)zm) - 1) : MAX_GT;

        // Y-band cull (conservative; R7 derivation)
        bool keep = (t < nv) &&
                    (jmaxf + 0.75f > ylo - 0.25f * gh - 1.0f) &&
                    (jminf - 0.75f < yhi + 0.25f * gh);
        unsigned long long km = __ballot(keep);
        if (keep) {
            int pos = (int)__popcll(km & ((1ull << t) - 1ull));
            s_gtA[pos] = make_float4(xlo, xhi, ylo, yhi);
            s_gtB[pos] = make_float4(gw, gh, KSIL * gw * gh, 0.f);
        }
        if (t == 0) s_nk = (int)__popcll(km);

        // scatter: last-write-wins = highest GT index (atomicMax, wave-local)
        int local = -1;
        if (t < nv && key >= 0) {
            int ae = key / PLANE;
            int l = (key - ae * PLANE) - cb * CPB;
            if (ae == a && l >= 0 && l < CPB) {
                local = l;
                atomicMax(&s_ovr[local], t);
            }
        }
        // winner check (atomicMax from this wave completed; same-wave order)
        if (local >= 0 && s_ovr[local] == t) {
            int idx = atomicAdd(&s_nce, 1);
            s_ce_cell[idx] = cb * CPB + local;
            s_ce_ov[idx] = t;
        }
    }
    __syncthreads();   // the ONLY pre-dense barrier

    const int nce = s_nce;
    const int wid = t >> 6, lane = t & 63;
    const float* cls_base = base + 5 * (size_t)PLANE;
    int ov = valid ? s_ovr[t] : -1;

    // ---- CE prefetch: one entry per wave (8 waves), issued BEFORE dense ----
    float ce1 = 0.f, ce2 = -3.4e38f, celt = 0.f;
    float q0 = 0.f, q1 = 0.f, q2 = 0.f, q3 = 0.f, q4 = 0.f;
    int pcell = 0, pov = 0;
    const bool havece = (wid < nce);
    if (havece) {
        pcell = s_ce_cell[wid];
        pov = s_ce_ov[wid];
        int ccls = (int)s_ent[pov][6];
        const float* cb0 = cls_base + pcell;
        ce1 = cb0[(size_t)lane * PLANE];
        if (lane < NC - 64) ce2 = cb0[(size_t)(lane + 64) * PLANE];
        celt = cb0[(size_t)ccls * PLANE];
        if (lane == 0) {
            q0 = base[pcell];
            q1 = base[pcell + PLANE];
            q2 = base[pcell + 2 * (size_t)PLANE];
            q3 = base[pcell + 3 * (size_t)PLANE];
            q4 = base[pcell + 4 * (size_t)PLANE];
        }
    }

    // ---- dense loss (1 cell) ----
    float loss = 0.f;
    if (valid) {
        int j = cell / NW, i = cell - (cell / NW) * NW;
        float x = fast_sigmoid(o0), y = fast_sigmoid(o1), cf = fast_sigmoid(o4);
        float pw = __expf(o2) * c_aw[a], ph = __expf(o3) * c_ah[a];
        float px = x + (float)i, py = y + (float)j;
        float xl = px - 0.5f * pw, xh = px + 0.5f * pw;
        float yl = py - 0.5f * ph, yh = py + 0.5f * ph;
        float kpa = KSIL * pw * ph;

        bool sil = false;
        int nk = s_nk;
        #pragma unroll 2
        for (int tt = 0; tt < nk; tt++) {
            float4 gA = s_gtA[tt];
            float4 gB = s_gtB[tt];
            float mx = fminf(xl, gA.x), Mx = fmaxf(xh, gA.y);
            float my = fminf(yl, gA.z), My = fmaxf(yh, gA.w);
            float cw = (pw + gB.x) - (Mx - mx);
            float ch = (ph + gB.y) - (My - my);
            sil |= (fminf(cw, ch) > 0.f) & (cw * ch > kpa + gB.z);
        }

        // conf term: non-GT cells only (GT-cell conf handled in CE phase)
        float cm = (ov >= 0) ? 0.f : (sil ? 0.f : 1.f);
        float tx = 0.5f, ty = 0.5f, tw = 0.f, th = 0.f;
        if (ov >= 0) {
            tx = s_ent[ov][1]; ty = s_ent[ov][2];
            tw = s_ent[ov][3]; th = s_ent[ov][4];
        }
        float dx = x - tx, dy = y - ty, dw = o2 - tw, dh = o3 - th;
        loss = 0.5f * (dx * dx + dy * dy + dw * dw + dh * dh + cm * cf * cf);
    }

    // ---- CE finish (prefetched entry): softmax-CE + deferred GT conf ----
    if (havece) {
        float m = fmaxf(ce1, ce2);
        #pragma unroll
        for (int off = 32; off; off >>= 1) m = fmaxf(m, __shfl_xor(m, off));
        float e = __expf(ce1 - m) + ((lane < NC - 64) ? __expf(ce2 - m) : 0.f);
        #pragma unroll
        for (int off = 32; off; off >>= 1) e += __shfl_xor(e, off);
        if (lane == 0) {
            int gjc = pcell / NW, gic = pcell - gjc * NW;
            float ppx = fast_sigmoid(q0) + (float)gic;
            float ppy = fast_sigmoid(q1) + (float)gjc;
            float ppw = __expf(q2) * s_ent[pov][10];
            float pph = __expf(q3) * s_ent[pov][11];
            float iou = iou_full(s_ent[pov][5], s_ent[pov][7],
                                 s_ent[pov][8], s_ent[pov][9],
                                 ppx, ppy, ppw, pph);
            float dcf = fast_sigmoid(q4) - iou;
            loss += m + __logf(e) - celt + 0.5f * OBJSC * dcf * dcf;
        }
    }
    // leftover CE entries (rare: >8 GT cells in one chunk)
    for (int k = wid + BLOCK / 64; k < nce; k += BLOCK / 64) {
        int ccell = s_ce_cell[k];
        int ovk = s_ce_ov[k];
        int ccls = (int)s_ent[ovk][6];
        const float* cb0 = cls_base + ccell;
        float w1 = cb0[(size_t)lane * PLANE];
        float w2 = (lane < NC - 64) ? cb0[(size_t)(lane + 64) * PLANE] : -3.4e38f;
        float m = fmaxf(w1, w2);
        #pragma unroll
        for (int off = 32; off; off >>= 1) m = fmaxf(m, __shfl_xor(m, off));
        float e = __expf(w1 - m) + ((lane < NC - 64) ? __expf(w2 - m) : 0.f);
        #pragma unroll
        for (int off = 32; off; off >>= 1) e += __shfl_xor(e, off);
        if (lane == 0) {
            int gjc = ccell / NW, gic = ccell - gjc * NW;
            float r0 = base[ccell];
            float r1 = base[ccell + PLANE];
            float r2 = base[ccell + 2 * (size_t)PLANE];
            float r3 = base[ccell + 3 * (size_t)PLANE];
            float r4 = base[ccell + 4 * (size_t)PLANE];
            float ppx = fast_sigmoid(r0) + (float)gic;
            float ppy = fast_sigmoid(r1) + (float)gjc;
            float ppw = __expf(r2) * s_ent[ovk][10];
            float pph = __expf(r3) * s_ent[ovk][11];
            float iou = iou_full(s_ent[ovk][5], s_ent[ovk][7],
                                 s_ent[ovk][8], s_ent[ovk][9],
                                 ppx, ppy, ppw, pph);
            float dcf = fast_sigmoid(r4) - iou;
            loss += m + __logf(e) - cb0[(size_t)ccls * PLANE]
                    + 0.5f * OBJSC * dcf * dcf;
        }
    }

    // ---- block reduction -> partial store ----
    #pragma unroll
    for (int off = 32; off; off >>= 1) loss += __shfl_down(loss, off);
    if (lane == 0) s_red[wid] = loss;
    __syncthreads();
    if (t == 0) {
        float s = 0.f;
        #pragma unroll
        for (int q = 0; q < BLOCK / 64; q++) s += s_red[q];
        partial[bid] = s;
    }
}

// Final reduction: ONE wave sums the 576 per-block partials (9 loads/lane).
__global__ __launch_bounds__(64) void yolo_reduce(const float* __restrict__ partial,
                                                  float* __restrict__ d_out) {
    int t = threadIdx.x;
    float s = 0.f;
    #pragma unroll
    for (int i = 0; i < GRID / 64; i++) s += partial[t + 64 * i];
    #pragma unroll
    for (int off = 32; off; off >>= 1) s += __shfl_down(s, off);
    if (t == 0) d_out[0] = s;
}

extern "C" void kernel_launch(void* const* d_in, const int* in_sizes, int n_in,
                              void* d_out, int out_size, void* d_ws, size_t ws_size,
                              hipStream_t stream) {
    const float* out = (const float*)d_in[0];
    const float* target = (const float*)d_in[1];
    float* partial = (float*)d_ws;
    float* o = (float*)d_out;

    hipLaunchKernelGGL(yolo_fused, dim3(GRID), dim3(BLOCK), 0, stream,
                       out, target, partial);
    hipLaunchKernelGGL(yolo_reduce, dim3(1), dim3(64), 0, stream,
                       partial, o);
}

// Round 13
// 14.649 us; speedup vs baseline: 1.5197x; 1.0521x over previous
//
#include <hip/hip_runtime.h>

#define NB 16
#define NA 3
#define NC 80
#define NH 76
#define NW 76
#define MAX_GT 50
#define PLANE (NH * NW)       // 5776
#define CH (5 + NC)           // 85
#define IMG 608.0f
#define OBJSC 5.0f
#define BLOCK 384                            // 6 waves
#define CPB 361                              // PLANE = 16*361 exactly
#define BPP 16
#define GRID (NB * NA * BPP)                 // 768 = exactly 3 blocks/CU on 256 CUs
#define KSIL 0.375f                          // SIL/(1+SIL), SIL=0.6

__device__ __constant__ float c_aw[3] = {1.5f, 2.375f, 5.0f};
__device__ __constant__ float c_ah[3] = {2.0f, 4.5f, 3.5f};

__device__ inline float fast_sigmoid(float v) {
    return __builtin_amdgcn_rcpf(1.f + __expf(-v));
}

__device__ inline float iou_full(float x1, float y1, float w1, float h1,
                                 float x2, float y2, float w2, float h2) {
    float mx = fminf(x1 - w1 * 0.5f, x2 - w2 * 0.5f);
    float Mx = fmaxf(x1 + w1 * 0.5f, x2 + w2 * 0.5f);
    float my = fminf(y1 - h1 * 0.5f, y2 - h2 * 0.5f);
    float My = fmaxf(y1 + h1 * 0.5f, y2 + h2 * 0.5f);
    float cw = w1 + w2 - (Mx - mx);
    float ch = h1 + h2 - (My - my);
    float carea = (cw <= 0.f || ch <= 0.f) ? 0.f : cw * ch;
    float uarea = w1 * h1 + w2 * h2 - carea;
    return carea / uarea;
}

// R12 skeleton, load-balanced: 768 blocks (exactly 3/CU), 384 threads,
// 1 cell/thread, CPB=361. Wave-0 prep+scatter+CE-list with ONE pre-dense
// barrier; CE prefetched per wave and hidden under the dense phase.
__global__ __launch_bounds__(BLOCK) void yolo_fused(const float* __restrict__ out,
                                                    const float* __restrict__ target,
                                                    float* __restrict__ partial) {
    const int bid = blockIdx.x;
    const int plane_id = bid / BPP;
    const int cb = bid % BPP;
    const int b = plane_id / NA;
    const int a = plane_id % NA;
    const int t = threadIdx.x;
    const int cell = cb * CPB + t;
    const bool valid = (t < CPB);            // 16*361 == PLANE: all cells real
    const float jminf = (float)((cb * CPB) / NW);
    const float jmaxf = (float)((cb * CPB + CPB - 1) / NW);

    __shared__ float4 s_gtA[MAX_GT];          // culled: xlo, xhi, ylo, yhi
    __shared__ float4 s_gtB[MAX_GT];          // culled: gw, gh, KSIL*area, 0
    __shared__ float s_ent[MAX_GT][12];       // 1:tx 2:ty 3:tw 4:th 5:gx 6:cls 7:gy 8:gw 9:gh 10:aw 11:ah
    __shared__ int s_ovr[BLOCK];              // local cell -> GT index (atomicMax); [361..384) unused
    __shared__ int s_ce_cell[MAX_GT];
    __shared__ int s_ce_ov[MAX_GT];
    __shared__ int s_nk, s_nce;
    __shared__ float s_red[BLOCK / 64];

    // ---- dense channel loads (scalar, coalesced), issued first ----
    const float* base = out + ((size_t)(b * NA + a) * CH) * PLANE;
    float o0 = 0.f, o1 = 0.f, o2 = 0.f, o3 = 0.f, o4 = 0.f;
    if (valid) {
        o0 = base[cell];
        o1 = base[cell + PLANE];
        o2 = base[cell + 2 * (size_t)PLANE];
        o3 = base[cell + 3 * (size_t)PLANE];
        o4 = base[cell + 4 * (size_t)PLANE];
    }

    // ---- wave 0: init + prep + scatter + winner/CE-list (no barriers) ----
    if (t < 64) {
        #pragma unroll
        for (int i = 0; i < BLOCK / 64; i++) s_ovr[t + 64 * i] = -1;
        if (t == 0) s_nce = 0;

        float pxr = 1.f;
        float xlo = 0.f, xhi = 0.f, ylo = 0.f, yhi = 0.f, gw = 0.f, gh = 0.f;
        int key = -1;
        if (t < MAX_GT) {
            const float* tg = target + (size_t)b * MAX_GT * 5 + t * 5;
            float gcls = tg[0];
            pxr = tg[1];
            float gx = tg[1] * (float)NW / IMG;
            float gy = tg[2] * (float)NH / IMG;
            gw = tg[3] * (float)NW / IMG;
            gh = tg[4] * (float)NH / IMG;
            xlo = gx - 0.5f * gw; xhi = gx + 0.5f * gw;
            ylo = gy - 0.5f * gh; yhi = gy + 0.5f * gh;

            int bn = 0; float best = -1.f;
            #pragma unroll
            for (int aa = 0; aa < NA; aa++) {
                float ca = fminf(gw, c_aw[aa]) * fminf(gh, c_ah[aa]);
                float ua = gw * gh + c_aw[aa] * c_ah[aa] - ca;
                float v = ca / ua;
                if (v > best) { best = v; bn = aa; }
            }
            int gi = (int)gx, gj = (int)gy;

            key = (gi >= 0 && gi < NW && gj >= 0 && gj < NH)
                      ? ((bn * NH + gj) * NW + gi) : -1;
            s_ent[t][1] = gx - (float)gi;
            s_ent[t][2] = gy - (float)gj;
            s_ent[t][3] = __logf(gw / c_aw[bn]);
            s_ent[t][4] = __logf(gh / c_ah[bn]);
            s_ent[t][5] = gx;
            s_ent[t][6] = gcls;
            s_ent[t][7] = gy;
            s_ent[t][8] = gw;
            s_ent[t][9] = gh;
            s_ent[t][10] = c_aw[bn];
            s_ent[t][11] = c_ah[bn];
        }
        unsigned long long zm = __ballot((t < MAX_GT) && (pxr == 0.f));
        int nv = zm ? (int)(__ffsll((long long)zm) - 1) : MAX_GT;

        // Y-band cull (conservative; R7 derivation)
        bool keep = (t < nv) &&
                    (jmaxf + 0.75f > ylo - 0.25f * gh - 1.0f) &&
                    (jminf - 0.75f < yhi + 0.25f * gh);
        unsigned long long km = __ballot(keep);
        if (keep) {
            int pos = (int)__popcll(km & ((1ull << t) - 1ull));
            s_gtA[pos] = make_float4(xlo, xhi, ylo, yhi);
            s_gtB[pos] = make_float4(gw, gh, KSIL * gw * gh, 0.f);
        }
        if (t == 0) s_nk = (int)__popcll(km);

        // scatter: last-write-wins = highest GT index (atomicMax, wave-local)
        int local = -1;
        if (t < nv && key >= 0) {
            int ae = key / PLANE;
            int l = (key - ae * PLANE) - cb * CPB;
            if (ae == a && l >= 0 && l < CPB) {
                local = l;
                atomicMax(&s_ovr[local], t);
            }
        }
        // winner check (atomicMax from this wave completed; same-wave order)
        if (local >= 0 && s_ovr[local] == t) {
            int idx = atomicAdd(&s_nce, 1);
            s_ce_cell[idx] = cb * CPB + local;
            s_ce_ov[idx] = t;
        }
    }
    __syncthreads();   // the ONLY pre-dense barrier

    const int nce = s_nce;
    const int wid = t >> 6, lane = t & 63;
    const float* cls_base = base + 5 * (size_t)PLANE;
    int ov = valid ? s_ovr[t] : -1;

    // ---- CE prefetch: one entry per wave (6 waves), issued BEFORE dense ----
    float ce1 = 0.f, ce2 = -3.4e38f, celt = 0.f;
    float q0 = 0.f, q1 = 0.f, q2 = 0.f, q3 = 0.f, q4 = 0.f;
    int pcell = 0, pov = 0;
    const bool havece = (wid < nce);
    if (havece) {
        pcell = s_ce_cell[wid];
        pov = s_ce_ov[wid];
        int ccls = (int)s_ent[pov][6];
        const float* cb0 = cls_base + pcell;
        ce1 = cb0[(size_t)lane * PLANE];
        if (lane < NC - 64) ce2 = cb0[(size_t)(lane + 64) * PLANE];
        celt = cb0[(size_t)ccls * PLANE];
        if (lane == 0) {
            q0 = base[pcell];
            q1 = base[pcell + PLANE];
            q2 = base[pcell + 2 * (size_t)PLANE];
            q3 = base[pcell + 3 * (size_t)PLANE];
            q4 = base[pcell + 4 * (size_t)PLANE];
        }
    }

    // ---- dense loss (1 cell) ----
    float loss = 0.f;
    if (valid) {
        int j = cell / NW, i = cell - (cell / NW) * NW;
        float x = fast_sigmoid(o0), y = fast_sigmoid(o1), cf = fast_sigmoid(o4);
        float pw = __expf(o2) * c_aw[a], ph = __expf(o3) * c_ah[a];
        float px = x + (float)i, py = y + (float)j;
        float xl = px - 0.5f * pw, xh = px + 0.5f * pw;
        float yl = py - 0.5f * ph, yh = py + 0.5f * ph;
        float kpa = KSIL * pw * ph;

        bool sil = false;
        int nk = s_nk;
        #pragma unroll 2
        for (int tt = 0; tt < nk; tt++) {
            float4 gA = s_gtA[tt];
            float4 gB = s_gtB[tt];
            float mx = fminf(xl, gA.x), Mx = fmaxf(xh, gA.y);
            float my = fminf(yl, gA.z), My = fmaxf(yh, gA.w);
            float cw = (pw + gB.x) - (Mx - mx);
            float ch = (ph + gB.y) - (My - my);
            sil |= (fminf(cw, ch) > 0.f) & (cw * ch > kpa + gB.z);
        }

        // conf term: non-GT cells only (GT-cell conf handled in CE phase)
        float cm = (ov >= 0) ? 0.f : (sil ? 0.f : 1.f);
        float tx = 0.5f, ty = 0.5f, tw = 0.f, th = 0.f;
        if (ov >= 0) {
            tx = s_ent[ov][1]; ty = s_ent[ov][2];
            tw = s_ent[ov][3]; th = s_ent[ov][4];
        }
        float dx = x - tx, dy = y - ty, dw = o2 - tw, dh = o3 - th;
        loss = 0.5f * (dx * dx + dy * dy + dw * dw + dh * dh + cm * cf * cf);
    }

    // ---- CE finish (prefetched entry): softmax-CE + deferred GT conf ----
    if (havece) {
        float m = fmaxf(ce1, ce2);
        #pragma unroll
        for (int off = 32; off; off >>= 1) m = fmaxf(m, __shfl_xor(m, off));
        float e = __expf(ce1 - m) + ((lane < NC - 64) ? __expf(ce2 - m) : 0.f);
        #pragma unroll
        for (int off = 32; off; off >>= 1) e += __shfl_xor(e, off);
        if (lane == 0) {
            int gjc = pcell / NW, gic = pcell - gjc * NW;
            float ppx = fast_sigmoid(q0) + (float)gic;
            float ppy = fast_sigmoid(q1) + (float)gjc;
            float ppw = __expf(q2) * s_ent[pov][10];
            float pph = __expf(q3) * s_ent[pov][11];
            float iou = iou_full(s_ent[pov][5], s_ent[pov][7],
                                 s_ent[pov][8], s_ent[pov][9],
                                 ppx, ppy, ppw, pph);
            float dcf = fast_sigmoid(q4) - iou;
            loss += m + __logf(e) - celt + 0.5f * OBJSC * dcf * dcf;
        }
    }
    // leftover CE entries (rare: >6 GT cells in one chunk)
    for (int k = wid + BLOCK / 64; k < nce; k += BLOCK / 64) {
        int ccell = s_ce_cell[k];
        int ovk = s_ce_ov[k];
        int ccls = (int)s_ent[ovk][6];
        const float* cb0 = cls_base + ccell;
        float w1 = cb0[(size_t)lane * PLANE];
        float w2 = (lane < NC - 64) ? cb0[(size_t)(lane + 64) * PLANE] : -3.4e38f;
        float m = fmaxf(w1, w2);
        #pragma unroll
        for (int off = 32; off; off >>= 1) m = fmaxf(m, __shfl_xor(m, off));
        float e = __expf(w1 - m) + ((lane < NC - 64) ? __expf(w2 - m) : 0.f);
        #pragma unroll
        for (int off = 32; off; off >>= 1) e += __shfl_xor(e, off);
        if (lane == 0) {
            int gjc = ccell / NW, gic = ccell - gjc * NW;
            float r0 = base[ccell];
            float r1 = base[ccell + PLANE];
            float r2 = base[ccell + 2 * (size_t)PLANE];
            float r3 = base[ccell + 3 * (size_t)PLANE];
            float r4 = base[ccell + 4 * (size_t)PLANE];
            float ppx = fast_sigmoid(r0) + (float)gic;
            float ppy = fast_sigmoid(r1) + (float)gjc;
            float ppw = __expf(r2) * s_ent[ovk][10];
            float pph = __expf(r3) * s_ent[ovk][11];
            float iou = iou_full(s_ent[ovk][5], s_ent[ovk][7],
                                 s_ent[ovk][8], s_ent[ovk][9],
                                 ppx, ppy, ppw, pph);
            float dcf = fast_sigmoid(r4) - iou;
            loss += m + __logf(e) - cb0[(size_t)ccls * PLANE]
                    + 0.5f * OBJSC * dcf * dcf;
        }
    }

    // ---- block reduction -> partial store ----
    #pragma unroll
    for (int off = 32; off; off >>= 1) loss += __shfl_down(loss, off);
    if (lane == 0) s_red[wid] = loss;
    __syncthreads();
    if (t == 0) {
        float s = 0.f;
        #pragma unroll
        for (int q = 0; q < BLOCK / 64; q++) s += s_red[q];
        partial[bid] = s;
    }
}

// Final reduction: ONE wave sums the 768 per-block partials (12 loads/lane).
__global__ __launch_bounds__(64) void yolo_reduce(const float* __restrict__ partial,
                                                  float* __restrict__ d_out) {
    int t = threadIdx.x;
    float s = 0.f;
    #pragma unroll
    for (int i = 0; i < GRID / 64; i++) s += partial[t + 64 * i];
    #pragma unroll
    for (int off = 32; off; off >>= 1) s += __shfl_down(s, off);
    if (t == 0) d_out[0] = s;
}

extern "C" void kernel_launch(void* const* d_in, const int* in_sizes, int n_in,
                              void* d_out, int out_size, void* d_ws, size_t ws_size,
                              hipStream_t stream) {
    const float* out = (const float*)d_in[0];
    const float* target = (const float*)d_in[1];
    float* partial = (float*)d_ws;
    float* o = (float*)d_out;

    hipLaunchKernelGGL(yolo_fused, dim3(GRID), dim3(BLOCK), 0, stream,
                       out, target, partial);
    hipLaunchKernelGGL(yolo_reduce, dim3(1), dim3(64), 0, stream,
                       partial, o);
}